// Round 1
// baseline (159.484 us; speedup 1.0000x reference)
//
#include <hip/hip_runtime.h>

// Problem constants (N=1, D=64, NCLS=21, R=C=512, R_IN=C_IN=256)
#define M_TOT 65536   // R_IN*C_IN
#define LBS_S 262144  // R*C

// ---------------------------------------------------------------------------
// Transpose feat (64, 65536) -> feat_t (65536, 64) so one spatial site is a
// contiguous 256B vector (coalesced lane-per-channel loads in the main kernel).
// ---------------------------------------------------------------------------
__global__ __launch_bounds__(256) void k_transpose_feat(const float* __restrict__ in,
                                                        float* __restrict__ out) {
  __shared__ float tile[64][65];  // +1 pad: conflict-free read-back
  const int s0 = blockIdx.x * 64;
  const int l = threadIdx.x & 63;
  const int w = threadIdx.x >> 6;
#pragma unroll
  for (int k = 0; k < 16; ++k) {
    const int d = w * 16 + k;
    tile[d][l] = in[(size_t)d * M_TOT + s0 + l];  // coalesced read
  }
  __syncthreads();
#pragma unroll
  for (int k = 0; k < 16; ++k) {
    const int s = w * 16 + k;
    out[(size_t)(s0 + s) * 64 + l] = tile[l][s];  // coalesced write
  }
}

// ---------------------------------------------------------------------------
// Transpose lbs (21, 262144) -> lbs_t (262144, 21): per-tap class vector is
// 84 contiguous bytes.
// ---------------------------------------------------------------------------
__global__ __launch_bounds__(256) void k_transpose_lbs(const float* __restrict__ in,
                                                       float* __restrict__ out) {
  const int s = blockIdx.x * blockDim.x + threadIdx.x;
  float v[21];
#pragma unroll
  for (int c = 0; c < 21; ++c) v[c] = in[(size_t)c * LBS_S + s];  // coalesced reads
#pragma unroll
  for (int c = 0; c < 21; ++c) out[(size_t)s * 21 + c] = v[c];    // wave-contiguous writes
}

// ---------------------------------------------------------------------------
// Main kernel: one wave per output pixel, lane = channel (D=64 == wave size).
// jax.image.resize(bilinear, 2x up) == sample at y=r/2-0.25 with edge clamp
// (boundary weight renormalization is identical to coordinate clamping).
// All 25 taps live in a 4x4 patch of the 256-grid: base=(rp-3)>>1.
// ---------------------------------------------------------------------------
__global__ __launch_bounds__(256) void k_main(const float* __restrict__ grid_inte,
                                              const float* __restrict__ grid,
                                              const float* __restrict__ feat_t,
                                              const float* __restrict__ lbs_t,
                                              const float* __restrict__ wei_p,
                                              float* __restrict__ out) {
  const int lane = threadIdx.x & 63;
  const int m = blockIdx.x * 4 + (threadIdx.x >> 6);

  // dx, dy from the meshgrid (both 1.0 for this problem, computed for fidelity)
  const float dx = grid[(2 * 512 + 2) * 2 + 0] - grid[(1 * 512 + 2) * 2 + 0];
  const float dy = grid[(2 * 512 + 2) * 2 + 1] - grid[(2 * 512 + 1) * 2 + 1];
  const float wei = wei_p[0];

  const float gi0 = grid_inte[m * 2 + 0];
  const float gi1 = grid_inte[m * 2 + 1];
  const int rp0 = (int)floorf(gi0 / dx);
  const int rp1 = (int)floorf(gi1 / dy);
  const int by = (rp0 - 3) >> 1;  // 4x4 patch base (may be <0; loads clamp)
  const int bx = (rp1 - 3) >> 1;

  // Per-channel 4x4 patch in registers (16 coalesced 256B wave loads)
  float P[4][4];
#pragma unroll
  for (int i = 0; i < 4; ++i) {
    const int yy = min(max(by + i, 0), 255);
#pragma unroll
    for (int j = 0; j < 4; ++j) {
      const int xx = min(max(bx + j, 0), 255);
      P[i][j] = feat_t[(size_t)(yy * 256 + xx) * 64 + lane];
    }
  }
  const float center = feat_t[(size_t)m * 64 + lane];

  // Wave-uniform tap parameters: 5 row offsets x 5 col offsets (separable)
  int py[5], px[5], row5[5], col5[5];
  float wy[5], wx[5];
#pragma unroll
  for (int k = 0; k < 5; ++k) {
    const int r5 = min(max(rp0 + (k - 2), 0), 511);
    row5[k] = r5;
    float y = fminf(fmaxf((float)r5 * 0.5f - 0.25f, 0.0f), 255.0f);
    const int y0 = min((int)y, 254);
    py[k] = y0 - by;            // in [0,2] by construction (verified both edges)
    wy[k] = y - (float)y0;

    const int c5 = min(max(rp1 + (k - 2), 0), 511);
    col5[k] = c5;
    float x = fminf(fmaxf((float)c5 * 0.5f - 0.25f, 0.0f), 255.0f);
    const int x0 = min((int)x, 254);
    px[k] = x0 - bx;
    wx[k] = x - (float)x0;
  }

  // Stage A: x-interp. px[k] is wave-uniform -> cndmask selects, no scratch.
  float colv[4][5];
#pragma unroll
  for (int k = 0; k < 5; ++k) {
    const int p = px[k];
#pragma unroll
    for (int r = 0; r < 4; ++r) {
      const float a = (p == 0) ? P[r][0] : ((p == 1) ? P[r][1] : P[r][2]);
      const float b = (p == 0) ? P[r][1] : ((p == 1) ? P[r][2] : P[r][3]);
      colv[r][k] = fmaf(wx[k], b - a, a);
    }
  }

  // Stage B: y-interp per tap, squared diff, 64-lane butterfly -> uniform mse,
  // then fused dist/vote/denom accumulation (lanes 0..20 own the 21 classes).
  float vote = 0.0f, denom = 0.0f;
  const float nscale = -wei * (1.0f / 64.0f);  // mean over D=64 channels
#pragma unroll
  for (int i = 0; i < 5; ++i) {
    const int q = py[i];
#pragma unroll
    for (int j = 0; j < 5; ++j) {
      const float a = (q == 0) ? colv[0][j] : ((q == 1) ? colv[1][j] : colv[2][j]);
      const float b = (q == 0) ? colv[1][j] : ((q == 1) ? colv[2][j] : colv[3][j]);
      const float v = fmaf(wy[i], b - a, a);
      float dsq = v - center;
      dsq *= dsq;
#pragma unroll
      for (int off = 1; off < 64; off <<= 1) dsq += __shfl_xor(dsq, off, 64);
      // dsq now wave-uniform = sum over 64 channels
      const float dist = __expf(nscale * dsq);
      denom += dist;
      const int idx = row5[i] * 512 + col5[j];
      const float lg = (lane < 21) ? lbs_t[(size_t)idx * 21 + lane] : 0.0f;
      vote = fmaf(lg, dist, vote);
    }
  }

  if (lane < 21) {
    out[(size_t)lane * M_TOT + m] = vote / fmaxf(denom, 1e-15f);
  }
}

extern "C" void kernel_launch(void* const* d_in, const int* in_sizes, int n_in,
                              void* d_out, int out_size, void* d_ws, size_t ws_size,
                              hipStream_t stream) {
  const float* grid_inte = (const float*)d_in[0];  // (1,256,256,2)
  const float* grid      = (const float*)d_in[1];  // (1,512,512,2)
  const float* feat      = (const float*)d_in[2];  // (1,64,256,256)
  const float* lbs       = (const float*)d_in[3];  // (1,21,512,512)
  const float* wei       = (const float*)d_in[4];  // scalar
  float* out = (float*)d_out;                      // (1,21,256,256)

  float* feat_t = (float*)d_ws;                    // 65536*64 f32 = 16 MB
  float* lbs_t  = feat_t + (size_t)M_TOT * 64;     // 262144*21 f32 = 21 MB

  hipLaunchKernelGGL(k_transpose_feat, dim3(M_TOT / 64), dim3(256), 0, stream, feat, feat_t);
  hipLaunchKernelGGL(k_transpose_lbs, dim3(LBS_S / 256), dim3(256), 0, stream, lbs, lbs_t);
  hipLaunchKernelGGL(k_main, dim3(M_TOT / 4), dim3(256), 0, stream,
                     grid_inte, grid, feat_t, lbs_t, wei, out);
}

// Round 2
// 107.214 us; speedup vs baseline: 1.4875x; 1.4875x over previous
//
#include <hip/hip_runtime.h>

// Problem constants (N=1, D=64, NCLS=21, R=C=512, R_IN=C_IN=256)
#define M_TOT 65536   // R_IN*C_IN
#define LBS_S 262144  // R*C

__device__ __forceinline__ int rfl(int v) { return __builtin_amdgcn_readfirstlane(v); }

// Multiplexed butterfly merge: lanes with `hi` continue reducing b, others a.
// After using lane-bit k at level k, value index bit k == lane bit k.
__device__ __forceinline__ float merge2(float a, float b, bool hi, int xo) {
  const float keep = hi ? b : a;
  const float send = hi ? a : b;
  return keep + __shfl_xor(send, xo, 64);
}

__device__ __forceinline__ float bperm(int lane_idx, float v) {
  return __int_as_float(__builtin_amdgcn_ds_bpermute(lane_idx << 2, __float_as_int(v)));
}

// ---------------------------------------------------------------------------
// feat (64, 65536) -> feat_t (65536, 64): one site = contiguous 256 B.
// ---------------------------------------------------------------------------
__global__ __launch_bounds__(256) void k_transpose_feat(const float* __restrict__ in,
                                                        float* __restrict__ out) {
  __shared__ float tile[64][65];
  const int s0 = blockIdx.x * 64;
  const int l = threadIdx.x & 63;
  const int w = threadIdx.x >> 6;
#pragma unroll
  for (int k = 0; k < 16; ++k) {
    const int d = w * 16 + k;
    tile[d][l] = in[(size_t)d * M_TOT + s0 + l];
  }
  __syncthreads();
#pragma unroll
  for (int k = 0; k < 16; ++k) {
    const int s = w * 16 + k;
    out[(size_t)(s0 + s) * 64 + l] = tile[l][s];
  }
}

// ---------------------------------------------------------------------------
// lbs (21, 262144) -> lbs_t (262144, 21): per-tap class vector = 84 B.
// ---------------------------------------------------------------------------
__global__ __launch_bounds__(256) void k_transpose_lbs(const float* __restrict__ in,
                                                       float* __restrict__ out) {
  const int s = blockIdx.x * blockDim.x + threadIdx.x;
  float v[21];
#pragma unroll
  for (int c = 0; c < 21; ++c) v[c] = in[(size_t)c * LBS_S + s];
#pragma unroll
  for (int c = 0; c < 21; ++c) out[(size_t)s * 21 + c] = v[c];
}

// ---------------------------------------------------------------------------
// N2[site] = ||feat_grid[:, site]||^2 for all 512x512 sites, stored quad-major:
// n2[((a*256+b)*4) + (ey*2+ex)] for site (2a+ey, 2b+ex). One wave per 2x2 quad,
// lane = channel; sources are the 3x3 neighborhood (a-1..a+1, b-1..b+1).
// ---------------------------------------------------------------------------
__global__ __launch_bounds__(256) void k_n2(const float* __restrict__ feat_t,
                                            float* __restrict__ n2) {
  const int lane = threadIdx.x & 63;
  const int quad = rfl(blockIdx.x * 4 + (threadIdx.x >> 6));
  const int a = quad >> 8;
  const int b = quad & 255;
  const int ra[3] = {max(a - 1, 0), a, min(a + 1, 255)};
  const int cb[3] = {max(b - 1, 0), b, min(b + 1, 255)};
  float F[3][3];
#pragma unroll
  for (int i = 0; i < 3; ++i)
#pragma unroll
    for (int j = 0; j < 3; ++j)
      F[i][j] = feat_t[(size_t)((ra[i] << 8) + cb[j]) * 64 + lane];

  // Per-axis upsample params for the two output parities (wave-uniform).
  float wye[2], wxe[2];
  int cye[2], cxe[2];
#pragma unroll
  for (int e = 0; e < 2; ++e) {
    const float yf = fminf(fmaxf((float)(2 * a + e) * 0.5f - 0.25f, 0.0f), 255.0f);
    const int y0 = min((int)yf, 254);
    wye[e] = yf - (float)y0;
    cye[e] = y0 - (a - 1);  // in {0,1}
    const float xf = fminf(fmaxf((float)(2 * b + e) * 0.5f - 0.25f, 0.0f), 255.0f);
    const int x0 = min((int)xf, 254);
    wxe[e] = xf - (float)x0;
    cxe[e] = x0 - (b - 1);
  }

  float colv[3][2];
#pragma unroll
  for (int r = 0; r < 3; ++r)
#pragma unroll
    for (int e = 0; e < 2; ++e) {
      const bool s1 = (cxe[e] == 1);
      const float A = s1 ? F[r][1] : F[r][0];
      const float B = s1 ? F[r][2] : F[r][1];
      colv[r][e] = fmaf(wxe[e], B - A, A);
    }

  float sq[4];
#pragma unroll
  for (int ey = 0; ey < 2; ++ey)
#pragma unroll
    for (int ex = 0; ex < 2; ++ex) {
      const bool s1 = (cye[ey] == 1);
      const float A = s1 ? colv[1][ex] : colv[0][ex];
      const float B = s1 ? colv[2][ex] : colv[1][ex];
      const float v = fmaf(wye[ey], B - A, A);
      sq[ey * 2 + ex] = v * v;
    }

  // Packed reduce: lane L (L&3 == ey*2+ex) ends with that site's norm.
  const bool h0 = lane & 1, h1 = lane & 2;
  float m0 = merge2(sq[0], sq[1], h0, 1);
  float m1 = merge2(sq[2], sq[3], h0, 1);
  float mm = merge2(m0, m1, h1, 2);
  mm += __shfl_xor(mm, 4, 64);
  mm += __shfl_xor(mm, 8, 64);
  mm += __shfl_xor(mm, 16, 64);
  mm += __shfl_xor(mm, 32, 64);
  if (lane < 4) n2[quad * 4 + lane] = mm;
}

// ---------------------------------------------------------------------------
// Main kernel (expanded form). One wave per pixel, lane = channel for the dot
// stage, lane = tap (0..24) for the tap stage.
//   mse_t = (N2[t] - 2 * Sum_s w_s(t) * D'_s) / 64,
//   D'_s  = F_s . c - 0.5*||c||^2   (Sum_s w_s == 1 folds the center norm in)
// ---------------------------------------------------------------------------
__global__ __launch_bounds__(256) void k_main(const float* __restrict__ grid_inte,
                                              const float* __restrict__ grid,
                                              const float* __restrict__ feat_t,
                                              const float* __restrict__ lbs_t,
                                              const float* __restrict__ n2,
                                              const float* __restrict__ wei_p,
                                              float* __restrict__ out) {
  const int lane = threadIdx.x & 63;
  const int m = rfl(blockIdx.x * 4 + (threadIdx.x >> 6));

  const float dx = grid[(2 * 512 + 2) * 2 + 0] - grid[(1 * 512 + 2) * 2 + 0];
  const float dy = grid[(2 * 512 + 2) * 2 + 1] - grid[(2 * 512 + 1) * 2 + 1];
  const float wei = wei_p[0];

  const float gi0 = grid_inte[m * 2 + 0];
  const float gi1 = grid_inte[m * 2 + 1];
  const int rp0 = rfl((int)floorf(gi0 / dx));
  const int rp1 = rfl((int)floorf(gi1 / dy));
  const int by = (rp0 - 3) >> 1;  // 4x4 patch base (scalar)
  const int bx = (rp1 - 3) >> 1;

  // 16 patch sites: scalar addresses, coalesced 256B wave loads.
  const float c = feat_t[m * 64 + lane];
  const float nh = -0.5f * c * c;
  float P[16];
#pragma unroll
  for (int i = 0; i < 4; ++i) {
    const int yy = min(max(by + i, 0), 255);
#pragma unroll
    for (int j = 0; j < 4; ++j) {
      const int xx = min(max(bx + j, 0), 255);
      P[i * 4 + j] = feat_t[((yy << 8) + xx) * 64 + lane];
    }
  }
  float pr[16];
#pragma unroll
  for (int s = 0; s < 16; ++s) pr[s] = fmaf(P[s], c, nh);

  // Multiplexed butterfly: lane L ends holding D'_{L&15} (s = sy*4+sx).
  const bool h0 = lane & 1, h1 = lane & 2, h2 = lane & 4, h3 = lane & 8;
  float r0[8];
#pragma unroll
  for (int k = 0; k < 8; ++k) r0[k] = merge2(pr[2 * k], pr[2 * k + 1], h0, 1);
  float r1[4];
#pragma unroll
  for (int k = 0; k < 4; ++k) r1[k] = merge2(r0[2 * k], r0[2 * k + 1], h1, 2);
  float r2[2];
#pragma unroll
  for (int k = 0; k < 2; ++k) r2[k] = merge2(r1[2 * k], r1[2 * k + 1], h2, 4);
  float Dv = merge2(r2[0], r2[1], h3, 8);
  Dv += __shfl_xor(Dv, 16, 64);
  Dv += __shfl_xor(Dv, 32, 64);

  // ---- Tap stage: lane t < 25 handles tap (i,j) = (t/5, t%5) ----
  const int t = lane;
  const int ti = (t * 13) >> 6;  // t/5 for t < 25
  const int tj = t - 5 * ti;
  const int r5 = min(max(rp0 + ti - 2, 0), 511);
  const int c5 = min(max(rp1 + tj - 2, 0), 511);
  const float yf = fminf(fmaxf((float)r5 * 0.5f - 0.25f, 0.0f), 255.0f);
  const int y0 = min((int)yf, 254);
  const float wy = yf - (float)y0;
  const int qy = y0 - by;  // in [0,2] for t<25
  const float xf = fminf(fmaxf((float)c5 * 0.5f - 0.25f, 0.0f), 255.0f);
  const int x0 = min((int)xf, 254);
  const float wx = xf - (float)x0;
  const int qx = x0 - bx;

  const float n2g = n2[(((r5 >> 1) << 8) + (c5 >> 1)) * 4 + ((r5 & 1) * 2 + (c5 & 1))];

  const int pbase = qy * 4 + qx;
  const float d00 = bperm(pbase, Dv);
  const float d01 = bperm(pbase + 1, Dv);
  const float d10 = bperm(pbase + 4, Dv);
  const float d11 = bperm(pbase + 5, Dv);
  const float lo = fmaf(wx, d01 - d00, d00);
  const float hi = fmaf(wx, d11 - d10, d10);
  const float crossD = fmaf(wy, hi - lo, lo);

  const float mse = fmaf(-2.0f, crossD, n2g) * 0.015625f;  // /64
  float dist = __expf(-wei * mse);
  dist = (t < 25) ? dist : 0.0f;

  float den = dist;
#pragma unroll
  for (int o = 1; o < 64; o <<= 1) den += __shfl_xor(den, o, 64);

  const int lidx = r5 * 512 + c5;
  float vote = 0.0f;
#pragma unroll
  for (int tt = 0; tt < 25; ++tt) {
    const int sidx = __builtin_amdgcn_readlane(lidx, tt);
    const float dt = __int_as_float(__builtin_amdgcn_readlane(__float_as_int(dist), tt));
    const float lg = (lane < 21) ? lbs_t[(size_t)sidx * 21 + lane] : 0.0f;
    vote = fmaf(lg, dt, vote);
  }

  if (lane < 21) out[lane * M_TOT + m] = vote / fmaxf(den, 1e-15f);
}

// ---------------------------------------------------------------------------
// Fallback (round-1 kernel) if workspace can't fit the extra 1 MB N2 table.
// ---------------------------------------------------------------------------
__global__ __launch_bounds__(256) void k_main_fb(const float* __restrict__ grid_inte,
                                                 const float* __restrict__ grid,
                                                 const float* __restrict__ feat_t,
                                                 const float* __restrict__ lbs_t,
                                                 const float* __restrict__ wei_p,
                                                 float* __restrict__ out) {
  const int lane = threadIdx.x & 63;
  const int m = blockIdx.x * 4 + (threadIdx.x >> 6);
  const float dx = grid[(2 * 512 + 2) * 2 + 0] - grid[(1 * 512 + 2) * 2 + 0];
  const float dy = grid[(2 * 512 + 2) * 2 + 1] - grid[(2 * 512 + 1) * 2 + 1];
  const float wei = wei_p[0];
  const float gi0 = grid_inte[m * 2 + 0];
  const float gi1 = grid_inte[m * 2 + 1];
  const int rp0 = (int)floorf(gi0 / dx);
  const int rp1 = (int)floorf(gi1 / dy);
  const int by = (rp0 - 3) >> 1;
  const int bx = (rp1 - 3) >> 1;
  float P[4][4];
#pragma unroll
  for (int i = 0; i < 4; ++i) {
    const int yy = min(max(by + i, 0), 255);
#pragma unroll
    for (int j = 0; j < 4; ++j) {
      const int xx = min(max(bx + j, 0), 255);
      P[i][j] = feat_t[(size_t)(yy * 256 + xx) * 64 + lane];
    }
  }
  const float center = feat_t[(size_t)m * 64 + lane];
  int py[5], px[5], row5[5], col5[5];
  float wy[5], wx[5];
#pragma unroll
  for (int k = 0; k < 5; ++k) {
    const int r5 = min(max(rp0 + (k - 2), 0), 511);
    row5[k] = r5;
    float y = fminf(fmaxf((float)r5 * 0.5f - 0.25f, 0.0f), 255.0f);
    const int y0 = min((int)y, 254);
    py[k] = y0 - by;
    wy[k] = y - (float)y0;
    const int c5 = min(max(rp1 + (k - 2), 0), 511);
    col5[k] = c5;
    float x = fminf(fmaxf((float)c5 * 0.5f - 0.25f, 0.0f), 255.0f);
    const int x0 = min((int)x, 254);
    px[k] = x0 - bx;
    wx[k] = x - (float)x0;
  }
  float colv[4][5];
#pragma unroll
  for (int k = 0; k < 5; ++k) {
    const int p = px[k];
#pragma unroll
    for (int r = 0; r < 4; ++r) {
      const float a = (p == 0) ? P[r][0] : ((p == 1) ? P[r][1] : P[r][2]);
      const float b = (p == 0) ? P[r][1] : ((p == 1) ? P[r][2] : P[r][3]);
      colv[r][k] = fmaf(wx[k], b - a, a);
    }
  }
  float vote = 0.0f, denom = 0.0f;
  const float nscale = -wei * (1.0f / 64.0f);
#pragma unroll
  for (int i = 0; i < 5; ++i) {
    const int q = py[i];
#pragma unroll
    for (int j = 0; j < 5; ++j) {
      const float a = (q == 0) ? colv[0][j] : ((q == 1) ? colv[1][j] : colv[2][j]);
      const float b = (q == 0) ? colv[1][j] : ((q == 1) ? colv[2][j] : colv[3][j]);
      const float v = fmaf(wy[i], b - a, a);
      float dsq = v - center;
      dsq *= dsq;
#pragma unroll
      for (int off = 1; off < 64; off <<= 1) dsq += __shfl_xor(dsq, off, 64);
      const float dist = __expf(nscale * dsq);
      denom += dist;
      const int idx = row5[i] * 512 + col5[j];
      const float lg = (lane < 21) ? lbs_t[(size_t)idx * 21 + lane] : 0.0f;
      vote = fmaf(lg, dist, vote);
    }
  }
  if (lane < 21) out[(size_t)lane * M_TOT + m] = vote / fmaxf(denom, 1e-15f);
}

extern "C" void kernel_launch(void* const* d_in, const int* in_sizes, int n_in,
                              void* d_out, int out_size, void* d_ws, size_t ws_size,
                              hipStream_t stream) {
  const float* grid_inte = (const float*)d_in[0];  // (1,256,256,2)
  const float* grid      = (const float*)d_in[1];  // (1,512,512,2)
  const float* feat      = (const float*)d_in[2];  // (1,64,256,256)
  const float* lbs       = (const float*)d_in[3];  // (1,21,512,512)
  const float* wei       = (const float*)d_in[4];  // scalar
  float* out = (float*)d_out;                      // (1,21,256,256)

  float* feat_t = (float*)d_ws;                        // 4,194,304 f32
  float* lbs_t  = feat_t + (size_t)M_TOT * 64;         // 5,505,024 f32
  float* n2v    = lbs_t + (size_t)LBS_S * 21;          // 262,144 f32
  const size_t need = ((size_t)M_TOT * 64 + (size_t)LBS_S * 21 + (size_t)LBS_S) * sizeof(float);

  hipLaunchKernelGGL(k_transpose_feat, dim3(M_TOT / 64), dim3(256), 0, stream, feat, feat_t);
  hipLaunchKernelGGL(k_transpose_lbs, dim3(LBS_S / 256), dim3(256), 0, stream, lbs, lbs_t);
  if (ws_size >= need) {
    hipLaunchKernelGGL(k_n2, dim3(M_TOT / 4), dim3(256), 0, stream, feat_t, n2v);
    hipLaunchKernelGGL(k_main, dim3(M_TOT / 4), dim3(256), 0, stream,
                       grid_inte, grid, feat_t, lbs_t, n2v, wei, out);
  } else {
    hipLaunchKernelGGL(k_main_fb, dim3(M_TOT / 4), dim3(256), 0, stream,
                       grid_inte, grid, feat_t, lbs_t, wei, out);
  }
}

// Round 3
// 71.914 us; speedup vs baseline: 2.2177x; 1.4909x over previous
//
#include <hip/hip_runtime.h>

// Problem constants (N=1, D=64, NCLS=21, R=C=512, R_IN=C_IN=256)
#define M_TOT 65536   // R_IN*C_IN
#define LBS_S 262144  // R*C

typedef _Float16 h2 __attribute__((ext_vector_type(2)));

__device__ __forceinline__ int rfl(int v) { return __builtin_amdgcn_readfirstlane(v); }
__device__ __forceinline__ float bperm(int l, float v) {
  return __int_as_float(__builtin_amdgcn_ds_bpermute(l << 2, __float_as_int(v)));
}
__device__ __forceinline__ int bpermi(int l, int v) {
  return __builtin_amdgcn_ds_bpermute(l << 2, v);
}
// Multiplexed butterfly merge (see round-2): lanes with `hi` keep reducing b.
__device__ __forceinline__ float merge2(float a, float b, bool hi, int xo) {
  const float keep = hi ? b : a;
  const float send = hi ? a : b;
  return keep + __shfl_xor(send, xo, 64);
}

#if __has_builtin(__builtin_amdgcn_fdot2)
__device__ __forceinline__ float fdot2(h2 a, h2 b, float c) {
  return __builtin_amdgcn_fdot2(a, b, c, false);
}
#else
__device__ __forceinline__ float fdot2(h2 a, h2 b, float c) {
  return fmaf((float)a.x, (float)b.x, fmaf((float)a.y, (float)b.y, c));
}
#endif

// ---------------------------------------------------------------------------
// feat (64, 65536) f32 -> feat_h (65536, 64) fp16: one site = 128 B.
// Write phase packs 2 channels/lane (half2), 2 sites per iteration.
// ---------------------------------------------------------------------------
__global__ __launch_bounds__(256) void k_transpose_feat(const float* __restrict__ in,
                                                        _Float16* __restrict__ out) {
  __shared__ float tile[64][65];
  const int s0 = blockIdx.x * 64;
  const int l = threadIdx.x & 63;
  const int w = threadIdx.x >> 6;
#pragma unroll
  for (int k = 0; k < 16; ++k) {
    const int d = w * 16 + k;
    tile[d][l] = in[(size_t)d * M_TOT + s0 + l];
  }
  __syncthreads();
  const int lh = l & 31, hs = l >> 5;
  h2* out2 = (h2*)out;
#pragma unroll
  for (int k = 0; k < 8; ++k) {
    const int s = w * 16 + 2 * k + hs;
    h2 v;
    v.x = (_Float16)tile[2 * lh][s];
    v.y = (_Float16)tile[2 * lh + 1][s];
    out2[(size_t)(s0 + s) * 32 + lh] = v;  // 256B coalesced
  }
}

// ---------------------------------------------------------------------------
// lbs (21, 262144) f32 -> lbs_h (262144, 21) fp16 (42 B per site).
// Per-wave LDS repack so global writes are contiguous dwords.
// ---------------------------------------------------------------------------
__global__ __launch_bounds__(256) void k_transpose_lbs(const float* __restrict__ in,
                                                       _Float16* __restrict__ out) {
  __shared__ _Float16 buf[4][64 * 21];  // 2688 B per wave
  const int l = threadIdx.x & 63;
  const int w = threadIdx.x >> 6;
  const int sb = blockIdx.x * 256 + w * 64;
#pragma unroll
  for (int c = 0; c < 21; ++c)
    buf[w][l * 21 + c] = (_Float16)in[(size_t)c * LBS_S + sb + l];
  __syncthreads();
  const uint32_t* src = (const uint32_t*)buf[w];
  uint32_t* dst = (uint32_t*)(out + (size_t)sb * 21);  // sb*42 bytes, dword-aligned
#pragma unroll
  for (int k = 0; k < 11; ++k) {
    const int i = k * 64 + l;
    if (i < 672) dst[i] = src[i];  // 672 dwords = 64 sites * 42 B
  }
}

// ---------------------------------------------------------------------------
// N2[site] = ||feat_grid[:, site]||^2 at all 512x512 sites, quad-major:
// n2[(a*256+b)*4 + (ey*2+ex)] for site (2a+ey, 2b+ex). One wave per quad.
// ---------------------------------------------------------------------------
__global__ __launch_bounds__(256) void k_n2(const _Float16* __restrict__ feat_h,
                                            float* __restrict__ n2) {
  const int lane = threadIdx.x & 63;
  const int quad = rfl(blockIdx.x * 4 + (threadIdx.x >> 6));
  const int a = quad >> 8;
  const int b = quad & 255;
  const int ra[3] = {max(a - 1, 0), a, min(a + 1, 255)};
  const int cb[3] = {max(b - 1, 0), b, min(b + 1, 255)};
  float F[3][3];
#pragma unroll
  for (int i = 0; i < 3; ++i)
#pragma unroll
    for (int j = 0; j < 3; ++j)
      F[i][j] = (float)feat_h[(size_t)((ra[i] << 8) + cb[j]) * 64 + lane];

  float wye[2], wxe[2];
  int cye[2], cxe[2];
#pragma unroll
  for (int e = 0; e < 2; ++e) {
    const float yf = fminf(fmaxf((float)(2 * a + e) * 0.5f - 0.25f, 0.0f), 255.0f);
    const int y0 = min((int)yf, 254);
    wye[e] = yf - (float)y0;
    cye[e] = y0 - (a - 1);
    const float xf = fminf(fmaxf((float)(2 * b + e) * 0.5f - 0.25f, 0.0f), 255.0f);
    const int x0 = min((int)xf, 254);
    wxe[e] = xf - (float)x0;
    cxe[e] = x0 - (b - 1);
  }

  float colv[3][2];
#pragma unroll
  for (int r = 0; r < 3; ++r)
#pragma unroll
    for (int e = 0; e < 2; ++e) {
      const bool s1 = (cxe[e] == 1);
      const float A = s1 ? F[r][1] : F[r][0];
      const float B = s1 ? F[r][2] : F[r][1];
      colv[r][e] = fmaf(wxe[e], B - A, A);
    }

  float sq[4];
#pragma unroll
  for (int ey = 0; ey < 2; ++ey)
#pragma unroll
    for (int ex = 0; ex < 2; ++ex) {
      const bool s1 = (cye[ey] == 1);
      const float A = s1 ? colv[1][ex] : colv[0][ex];
      const float B = s1 ? colv[2][ex] : colv[1][ex];
      const float v = fmaf(wye[ey], B - A, A);
      sq[ey * 2 + ex] = v * v;
    }

  const bool h0 = lane & 1, h1 = lane & 2;
  float m0 = merge2(sq[0], sq[1], h0, 1);
  float m1 = merge2(sq[2], sq[3], h0, 1);
  float mm = merge2(m0, m1, h1, 2);
  mm += __shfl_xor(mm, 4, 64);
  mm += __shfl_xor(mm, 8, 64);
  mm += __shfl_xor(mm, 16, 64);
  mm += __shfl_xor(mm, 32, 64);
  if (lane < 4) n2[quad * 4 + lane] = mm;
}

// ---------------------------------------------------------------------------
// Main kernel. One wave per pixel.
// Dot stage: lanes 0-31 site 2k, lanes 32-63 site 2k+1; 2 channels/lane via
// v_dot2_f32_f16. After the 32-lane multiplexed butterfly, lane L holds
// D'_s for s = 2*(L&7) + (L>>5), where D'_s = F_s.c - 0.5*||c||^2.
// Tap stage: lane t < 25 handles tap (t/5, t%5); mse = (N2 - 2*interp(D'))/64.
// Vote stage: 3 taps x 21 classes in parallel (9 iterations).
// ---------------------------------------------------------------------------
__global__ __launch_bounds__(256) void k_main(const float* __restrict__ grid_inte,
                                              const float* __restrict__ grid,
                                              const _Float16* __restrict__ feat_h,
                                              const _Float16* __restrict__ lbs_h,
                                              const float* __restrict__ n2,
                                              const float* __restrict__ wei_p,
                                              float* __restrict__ out) {
  const int lane = threadIdx.x & 63;
  const int m = rfl(blockIdx.x * 4 + (threadIdx.x >> 6));

  const float dx = grid[(2 * 512 + 2) * 2 + 0] - grid[(1 * 512 + 2) * 2 + 0];
  const float dy = grid[(2 * 512 + 2) * 2 + 1] - grid[(2 * 512 + 1) * 2 + 1];
  const float wei = wei_p[0];

  const float gi0 = grid_inte[m * 2 + 0];
  const float gi1 = grid_inte[m * 2 + 1];
  const int rp0 = rfl((int)floorf(gi0 / dx));
  const int rp1 = rfl((int)floorf(gi1 / dy));
  const int by = (rp0 - 3) >> 1;  // 4x4 patch base (scalar)
  const int bx = (rp1 - 3) >> 1;

  const int lh = lane & 31;
  const int hs = lane >> 5;
  const h2* fh2 = (const h2*)feat_h;

  const h2 c2 = fh2[(size_t)m * 32 + lh];          // channels (2lh, 2lh+1)
  const float nh = -0.5f * fdot2(c2, c2, 0.0f);

  float pr[8];
#pragma unroll
  for (int k = 0; k < 8; ++k) {
    const int yy = min(max(by + (k >> 1), 0), 255);          // scalar
    const int xx = min(max(bx + ((2 * k) & 3) + hs, 0), 255);
    const h2 p = fh2[((yy << 8) + xx) * 32 + lh];            // 256B coalesced
    pr[k] = fdot2(p, c2, nh);
  }

  const bool h0 = lane & 1, h1 = lane & 2, h2b = lane & 4;
  float r0[4];
#pragma unroll
  for (int k = 0; k < 4; ++k) r0[k] = merge2(pr[2 * k], pr[2 * k + 1], h0, 1);
  float r1[2];
#pragma unroll
  for (int k = 0; k < 2; ++k) r1[k] = merge2(r0[2 * k], r0[2 * k + 1], h1, 2);
  float Dv = merge2(r1[0], r1[1], h2b, 4);
  Dv += __shfl_xor(Dv, 8, 64);
  Dv += __shfl_xor(Dv, 16, 64);
  // lane L holds D'_s, s = 2*(L&7) + (L>>5)

  // ---- Tap stage: lane t handles tap (ti, tj) ----
  const int t = lane;
  const int ti = (t * 13) >> 6;  // t/5 for t < 25
  const int tj = t - 5 * ti;
  const int r5 = min(max(rp0 + ti - 2, 0), 511);
  const int c5 = min(max(rp1 + tj - 2, 0), 511);
  const float yf = fminf(fmaxf((float)r5 * 0.5f - 0.25f, 0.0f), 255.0f);
  const int y0 = min((int)yf, 254);
  const float wy = yf - (float)y0;
  const int qy = y0 - by;  // in [0,2] for t<25
  const float xf = fminf(fmaxf((float)c5 * 0.5f - 0.25f, 0.0f), 255.0f);
  const int x0 = min((int)xf, 254);
  const float wx = xf - (float)x0;
  const int qx = x0 - bx;

  const float n2g = n2[(((r5 >> 1) << 8) + (c5 >> 1)) * 4 + ((r5 & 1) * 2 + (c5 & 1))];

  const int s00 = qy * 4 + qx;
  const int s01 = s00 + 1, s10 = s00 + 4, s11 = s00 + 5;
  const int l00 = (s00 >> 1) | ((s00 & 1) << 5);
  const int l01 = (s01 >> 1) | ((s01 & 1) << 5);
  const int l10 = (s10 >> 1) | ((s10 & 1) << 5);
  const int l11 = (s11 >> 1) | ((s11 & 1) << 5);
  const float d00 = bperm(l00, Dv);
  const float d01 = bperm(l01, Dv);
  const float d10 = bperm(l10, Dv);
  const float d11 = bperm(l11, Dv);
  const float lo = fmaf(wx, d01 - d00, d00);
  const float hi = fmaf(wx, d11 - d10, d10);
  const float crossD = fmaf(wy, hi - lo, lo);

  const float mse = fmaf(-2.0f, crossD, n2g) * 0.015625f;  // /64
  float dist = __expf(-wei * mse);
  dist = (t < 25) ? dist : 0.0f;

  const int lidx = r5 * 512 + c5;

  float den = dist;
#pragma unroll
  for (int o = 1; o < 64; o <<= 1) den += __shfl_xor(den, o, 64);

  // ---- Vote stage: lane = (group g of 3 taps) x (class cc) ----
  const int g = (lane >= 42) ? 2 : ((lane >= 21) ? 1 : 0);
  const int cc = min(lane - 21 * g, 20);
  float vote = 0.0f;
#pragma unroll
  for (int it = 0; it < 9; ++it) {
    const int tt = 3 * it + g;           // taps 25,26 have dist==0
    const float dt = bperm(tt, dist);
    const int idxt = bpermi(tt, lidx);   // clamped coords -> always in-bounds
    const float lg = (float)lbs_h[idxt * 21 + cc];
    vote = fmaf(lg, dt, vote);
  }
  const float va = bperm(lane + 21, vote);
  const float vb = bperm(lane + 42, vote);
  const float vtot = vote + va + vb;

  if (lane < 21) out[lane * M_TOT + m] = vtot / fmaxf(den, 1e-15f);
}

extern "C" void kernel_launch(void* const* d_in, const int* in_sizes, int n_in,
                              void* d_out, int out_size, void* d_ws, size_t ws_size,
                              hipStream_t stream) {
  const float* grid_inte = (const float*)d_in[0];  // (1,256,256,2)
  const float* grid      = (const float*)d_in[1];  // (1,512,512,2)
  const float* feat      = (const float*)d_in[2];  // (1,64,256,256)
  const float* lbs       = (const float*)d_in[3];  // (1,21,512,512)
  const float* wei       = (const float*)d_in[4];  // scalar
  float* out = (float*)d_out;                      // (1,21,256,256)

  _Float16* feat_h = (_Float16*)d_ws;                      // 8 MB
  _Float16* lbs_h  = feat_h + (size_t)M_TOT * 64;          // 10.5 MB
  float*    n2v    = (float*)(lbs_h + (size_t)LBS_S * 21); // 1 MB

  hipLaunchKernelGGL(k_transpose_feat, dim3(M_TOT / 64), dim3(256), 0, stream, feat, feat_h);
  hipLaunchKernelGGL(k_transpose_lbs, dim3(LBS_S / 256), dim3(256), 0, stream, lbs, lbs_h);
  hipLaunchKernelGGL(k_n2, dim3(M_TOT / 4), dim3(256), 0, stream, feat_h, n2v);
  hipLaunchKernelGGL(k_main, dim3(M_TOT / 4), dim3(256), 0, stream,
                     grid_inte, grid, feat_h, lbs_h, n2v, wei, out);
}

// Round 4
// 60.343 us; speedup vs baseline: 2.6429x; 1.1918x over previous
//
#include <hip/hip_runtime.h>

// Problem constants (N=1, D=64, NCLS=21, R=C=512, R_IN=C_IN=256)
#define M_TOT 65536   // R_IN*C_IN
#define LBS_S 262144  // R*C

typedef _Float16 h2 __attribute__((ext_vector_type(2)));
typedef _Float16 h8 __attribute__((ext_vector_type(8)));
union H8 { h8 v; h2 h[4]; };

__device__ __forceinline__ int rfl(int v) { return __builtin_amdgcn_readfirstlane(v); }
__device__ __forceinline__ float bperm(int l, float v) {
  return __int_as_float(__builtin_amdgcn_ds_bpermute(l << 2, __float_as_int(v)));
}
__device__ __forceinline__ int bpermi(int l, int v) {
  return __builtin_amdgcn_ds_bpermute(l << 2, v);
}
// Multiplexed butterfly merge: lanes with `hi` keep reducing b, others a.
__device__ __forceinline__ float merge2(float a, float b, bool hi, int xo) {
  const float keep = hi ? b : a;
  const float send = hi ? a : b;
  return keep + __shfl_xor(send, xo, 64);
}

#if __has_builtin(__builtin_amdgcn_fdot2)
__device__ __forceinline__ float fdot2(h2 a, h2 b, float c) {
  return __builtin_amdgcn_fdot2(a, b, c, false);
}
#else
__device__ __forceinline__ float fdot2(h2 a, h2 b, float c) {
  return fmaf((float)a.x, (float)b.x, fmaf((float)a.y, (float)b.y, c));
}
#endif

// ---------------------------------------------------------------------------
// Fused prep: blocks 0-1023 transpose feat (64,65536)f32 -> (65536,64)fp16;
// blocks 1024-2047 transpose lbs (21,262144)f32 -> (262144,21)fp16.
// ---------------------------------------------------------------------------
__global__ __launch_bounds__(256) void k_prep(const float* __restrict__ feat,
                                              const float* __restrict__ lbs,
                                              _Float16* __restrict__ feat_h,
                                              _Float16* __restrict__ lbs_h) {
  __shared__ float ldsf[64 * 65];  // 16640 B, reused by both branches
  const int l = threadIdx.x & 63;
  const int w = threadIdx.x >> 6;
  if (blockIdx.x < 1024) {
    float(*tile)[65] = (float(*)[65])ldsf;
    const int s0 = blockIdx.x * 64;
#pragma unroll
    for (int k = 0; k < 16; ++k) {
      const int d = w * 16 + k;
      tile[d][l] = feat[(size_t)d * M_TOT + s0 + l];
    }
    __syncthreads();
    const int lh = l & 31, hs = l >> 5;
    h2* out2 = (h2*)feat_h;
#pragma unroll
    for (int k = 0; k < 8; ++k) {
      const int s = w * 16 + 2 * k + hs;
      h2 v;
      v.x = (_Float16)tile[2 * lh][s];
      v.y = (_Float16)tile[2 * lh + 1][s];
      out2[(size_t)(s0 + s) * 32 + lh] = v;  // 256B coalesced
    }
  } else {
    _Float16* buf = ((_Float16*)ldsf) + w * (64 * 21);
    const int sb = (blockIdx.x - 1024) * 256 + w * 64;
#pragma unroll
    for (int c = 0; c < 21; ++c)
      buf[l * 21 + c] = (_Float16)lbs[(size_t)c * LBS_S + sb + l];
    __syncthreads();
    const uint32_t* src = (const uint32_t*)buf;
    uint32_t* dst = (uint32_t*)(lbs_h + (size_t)sb * 21);  // sb*42 B, dword-aligned
#pragma unroll
    for (int k = 0; k < 11; ++k) {
      const int i = k * 64 + l;
      if (i < 672) dst[i] = src[i];  // 672 dwords = 64 sites * 42 B
    }
  }
}

// ---------------------------------------------------------------------------
// N2[site] = ||feat_grid[:, site]||^2, quad-major: n2[(a*256+b)*4 + ey*2+ex].
// 8 quads per wave: lane = (group g = L>>3 -> quad, channel-block cb = L&7).
// Interp in packed fp16 (v_pk_*), square-accumulate via fdot2 into f32.
// ---------------------------------------------------------------------------
__global__ __launch_bounds__(256) void k_n2(const _Float16* __restrict__ feat_h,
                                            float* __restrict__ n2) {
  const int lane = threadIdx.x & 63;
  const int cb = lane & 7;
  const int g = lane >> 3;
  const int quad = blockIdx.x * 32 + (int)(threadIdx.x >> 6) * 8 + g;
  const int a = quad >> 8;
  const int b = quad & 255;
  const int ra[3] = {max(a - 1, 0), a, min(a + 1, 255)};
  const int cbn[3] = {max(b - 1, 0), b, min(b + 1, 255)};

  const h8* fp = (const h8*)feat_h;
  H8 F[3][3];
#pragma unroll
  for (int i = 0; i < 3; ++i)
#pragma unroll
    for (int j = 0; j < 3; ++j)
      F[i][j].v = fp[(size_t)((ra[i] << 8) + cbn[j]) * 8 + cb];

  // Upsample params for the 2 parities on each axis (per-lane/quad uniform).
  h2 wyh[2], wxh[2];
  int cye[2], cxe[2];
#pragma unroll
  for (int e = 0; e < 2; ++e) {
    const float yf = fminf(fmaxf((float)(2 * a + e) * 0.5f - 0.25f, 0.0f), 255.0f);
    const int y0 = min((int)yf, 254);
    wyh[e].x = wyh[e].y = (_Float16)(yf - (float)y0);
    cye[e] = y0 - (a - 1);
    const float xf = fminf(fmaxf((float)(2 * b + e) * 0.5f - 0.25f, 0.0f), 255.0f);
    const int x0 = min((int)xf, 254);
    wxh[e].x = wxh[e].y = (_Float16)(xf - (float)x0);
    cxe[e] = x0 - (b - 1);
  }

  H8 colv[3][2];
#pragma unroll
  for (int r = 0; r < 3; ++r)
#pragma unroll
    for (int e = 0; e < 2; ++e) {
      const bool s1 = (cxe[e] == 1);
#pragma unroll
      for (int q = 0; q < 4; ++q) {
        const h2 A = s1 ? F[r][1].h[q] : F[r][0].h[q];
        const h2 B = s1 ? F[r][2].h[q] : F[r][1].h[q];
        colv[r][e].h[q] = A + wxh[e] * (B - A);
      }
    }

  float sq[4];
#pragma unroll
  for (int ey = 0; ey < 2; ++ey)
#pragma unroll
    for (int ex = 0; ex < 2; ++ex) {
      const bool s1 = (cye[ey] == 1);
      float nn = 0.0f;
#pragma unroll
      for (int q = 0; q < 4; ++q) {
        const h2 A = s1 ? colv[1][ex].h[q] : colv[0][ex].h[q];
        const h2 B = s1 ? colv[2][ex].h[q] : colv[1][ex].h[q];
        const h2 v = A + wyh[ey] * (B - A);
        nn = fdot2(v, v, nn);
      }
      sq[ey * 2 + ex] = nn;
    }

  // Reduce 4 values over the 8 cb-lanes (bits 0-2), multiplexed.
  const bool b0 = lane & 1, b1 = lane & 2;
  float m0 = merge2(sq[0], sq[1], b0, 1);
  float m1 = merge2(sq[2], sq[3], b0, 1);
  float mm = merge2(m0, m1, b1, 2);
  mm += __shfl_xor(mm, 4, 64);
  // lane holds output o = L&3 for its quad (lanes o and o+4 duplicate)
  if ((lane & 7) < 4) n2[quad * 4 + (lane & 3)] = mm;
}

// ---------------------------------------------------------------------------
// Main kernel. One wave per pixel.
// Dot stage: lane = (site-group g = L>>3, channel-block cb = L&7); 8 ch/lane
// via dwordx4 + 4x fdot2. Two loads cover all 16 patch sites. After the
// 3-level reduce, lane L holds D'_s for s = 8*(L&1) + (L>>3),
// D'_s = F_s.c - 0.5*||c||^2.
// Tap stage: lane t < 25 handles tap (t/5, t%5); mse = (N2 - 2*interp(D'))/64.
// Vote stage: 3 taps x 21 classes in parallel (9 iterations).
// ---------------------------------------------------------------------------
__global__ __launch_bounds__(256) void k_main(const float* __restrict__ grid_inte,
                                              const float* __restrict__ grid,
                                              const _Float16* __restrict__ feat_h,
                                              const _Float16* __restrict__ lbs_h,
                                              const float* __restrict__ n2,
                                              const float* __restrict__ wei_p,
                                              float* __restrict__ out) {
  const int lane = threadIdx.x & 63;
  const int m = rfl(blockIdx.x * 4 + (threadIdx.x >> 6));

  const float dx = grid[(2 * 512 + 2) * 2 + 0] - grid[(1 * 512 + 2) * 2 + 0];
  const float dy = grid[(2 * 512 + 2) * 2 + 1] - grid[(2 * 512 + 1) * 2 + 1];
  const float wei = wei_p[0];

  const float gi0 = grid_inte[m * 2 + 0];
  const float gi1 = grid_inte[m * 2 + 1];
  const int rp0 = rfl((int)floorf(gi0 / dx));
  const int rp1 = rfl((int)floorf(gi1 / dy));
  const int by = (rp0 - 3) >> 1;  // 4x4 patch base (scalar)
  const int bx = (rp1 - 3) >> 1;

  const int cb = lane & 7;
  const int g = lane >> 3;
  const h8* fp = (const h8*)feat_h;

  // Center channels 8cb..8cb+7
  H8 C;
  C.v = fp[(size_t)m * 8 + cb];
  float nhp = 0.0f;
#pragma unroll
  for (int q = 0; q < 4; ++q) nhp = fdot2(C.h[q], C.h[q], nhp);
  nhp *= -0.5f;

  float p[2];
#pragma unroll
  for (int k = 0; k < 2; ++k) {
    const int s = k * 8 + g;
    const int yy = min(max(by + (s >> 2), 0), 255);
    const int xx = min(max(bx + (s & 3), 0), 255);
    H8 P;
    P.v = fp[(size_t)((yy << 8) + xx) * 8 + cb];
    float acc = nhp;
#pragma unroll
    for (int q = 0; q < 4; ++q) acc = fdot2(P.h[q], C.h[q], acc);
    p[k] = acc;
  }

  // Reduce over the 8 cb-lanes (bits 0-2), multiplexing the 2 site-groups.
  float Dv = merge2(p[0], p[1], lane & 1, 1);
  Dv += __shfl_xor(Dv, 2, 64);
  Dv += __shfl_xor(Dv, 4, 64);
  // lane L holds D'_s, s = 8*(L&1) + (L>>3); source lane for s: ((s&7)<<3)|(s>>3)

  // ---- Tap stage: lane t handles tap (ti, tj) ----
  const int t = lane;
  const int ti = (t * 13) >> 6;  // t/5 for t < 25
  const int tj = t - 5 * ti;
  const int r5 = min(max(rp0 + ti - 2, 0), 511);
  const int c5 = min(max(rp1 + tj - 2, 0), 511);
  const float yf = fminf(fmaxf((float)r5 * 0.5f - 0.25f, 0.0f), 255.0f);
  const int y0 = min((int)yf, 254);
  const float wy = yf - (float)y0;
  const int qy = y0 - by;  // in [0,2] for t<25
  const float xf = fminf(fmaxf((float)c5 * 0.5f - 0.25f, 0.0f), 255.0f);
  const int x0 = min((int)xf, 254);
  const float wx = xf - (float)x0;
  const int qx = x0 - bx;

  const float n2g = n2[(((r5 >> 1) << 8) + (c5 >> 1)) * 4 + ((r5 & 1) * 2 + (c5 & 1))];

  const int s00 = qy * 4 + qx;
  const int s01 = s00 + 1, s10 = s00 + 4, s11 = s00 + 5;
  const int l00 = ((s00 & 7) << 3) | (s00 >> 3);
  const int l01 = ((s01 & 7) << 3) | (s01 >> 3);
  const int l10 = ((s10 & 7) << 3) | (s10 >> 3);
  const int l11 = ((s11 & 7) << 3) | (s11 >> 3);
  const float d00 = bperm(l00, Dv);
  const float d01 = bperm(l01, Dv);
  const float d10 = bperm(l10, Dv);
  const float d11 = bperm(l11, Dv);
  const float lo = fmaf(wx, d01 - d00, d00);
  const float hi = fmaf(wx, d11 - d10, d10);
  const float crossD = fmaf(wy, hi - lo, lo);

  const float mse = fmaf(-2.0f, crossD, n2g) * 0.015625f;  // /64
  float dist = __expf(-wei * mse);
  dist = (t < 25) ? dist : 0.0f;

  const int lidx = r5 * 512 + c5;

  float den = dist;
#pragma unroll
  for (int o = 1; o < 64; o <<= 1) den += __shfl_xor(den, o, 64);

  // ---- Vote stage: lane = (group g of 3 taps) x (class cc) ----
  const int vg = (lane >= 42) ? 2 : ((lane >= 21) ? 1 : 0);
  const int cc = min(lane - 21 * vg, 20);
  float vote = 0.0f;
#pragma unroll
  for (int it = 0; it < 9; ++it) {
    const int tt = 3 * it + vg;          // taps 25,26 have dist==0
    const float dt = bperm(tt, dist);
    const int idxt = bpermi(tt, lidx);   // clamped coords -> always in-bounds
    const float lg = (float)lbs_h[idxt * 21 + cc];
    vote = fmaf(lg, dt, vote);
  }
  const float va = bperm(lane + 21, vote);
  const float vb = bperm(lane + 42, vote);
  const float vtot = vote + va + vb;

  if (lane < 21) out[lane * M_TOT + m] = vtot / fmaxf(den, 1e-15f);
}

extern "C" void kernel_launch(void* const* d_in, const int* in_sizes, int n_in,
                              void* d_out, int out_size, void* d_ws, size_t ws_size,
                              hipStream_t stream) {
  const float* grid_inte = (const float*)d_in[0];  // (1,256,256,2)
  const float* grid      = (const float*)d_in[1];  // (1,512,512,2)
  const float* feat      = (const float*)d_in[2];  // (1,64,256,256)
  const float* lbs       = (const float*)d_in[3];  // (1,21,512,512)
  const float* wei       = (const float*)d_in[4];  // scalar
  float* out = (float*)d_out;                      // (1,21,256,256)

  _Float16* feat_h = (_Float16*)d_ws;                      // 8 MB
  _Float16* lbs_h  = feat_h + (size_t)M_TOT * 64;          // 10.5 MB
  float*    n2v    = (float*)(lbs_h + (size_t)LBS_S * 21); // 1 MB

  hipLaunchKernelGGL(k_prep, dim3(2048), dim3(256), 0, stream, feat, lbs, feat_h, lbs_h);
  hipLaunchKernelGGL(k_n2, dim3(M_TOT / 32), dim3(256), 0, stream, feat_h, n2v);
  hipLaunchKernelGGL(k_main, dim3(M_TOT / 4), dim3(256), 0, stream,
                     grid_inte, grid, feat_h, lbs_h, n2v, wei, out);
}